// Round 18
// baseline (630.644 us; speedup 1.0000x reference)
//
#include <hip/hip_runtime.h>

#define CNUM 1024
#define CDIM 256
#define EPS_CAND 6.0f

// out region offsets in FP32 elements (zbar, zsoft, zhard, symbols, phisoft)
#define OFF_ZBAR   ((size_t)0)
#define OFF_ZSOFT  ((size_t)16777216)
#define OFF_ZHARD  ((size_t)33554432)
#define OFF_SYM    ((size_t)50331648)
#define OFF_PHI    ((size_t)50397184)

typedef __attribute__((ext_vector_type(8))) short bf16x8;
typedef __attribute__((ext_vector_type(4))) float f32x4;
typedef __attribute__((ext_vector_type(4))) unsigned short u16x4;

__device__ __forceinline__ unsigned short f2bf(float f){
  unsigned u = __float_as_uint(f);
  u += 0x7fffu + ((u >> 16) & 1u);
  return (unsigned short)(u >> 16);
}
__device__ __forceinline__ float bf2f(unsigned short h){
  return __uint_as_float(((unsigned)h) << 16);
}
__device__ __forceinline__ float clamp01(float v){ return fminf(1.0f, fmaxf(0.0f, v)); }
__device__ __forceinline__ float clamp11(float v){ return fminf(1.0f, fmaxf(-1.0f, v)); }
__device__ __forceinline__ float dot4(float4 a, float4 b){ return a.x*b.x + a.y*b.y + a.z*b.z + a.w*b.w; }

// ---------- prep ----------
__global__ __launch_bounds__(256) void prep_convert(const float* __restrict__ centers,
                                                    unsigned short* __restrict__ cb16,
                                                    unsigned short* __restrict__ ct16){
  int gid = blockIdx.x*256 + threadIdx.x;
  int c = gid >> 6, d0 = (gid & 63)*4;
  float4 v = *reinterpret_cast<const float4*>(centers + (size_t)c*CDIM + d0);
  unsigned short b0=f2bf(v.x), b1=f2bf(v.y), b2=f2bf(v.z), b3=f2bf(v.w);
  unsigned lo = (unsigned)b0 | ((unsigned)b1<<16);
  unsigned hi = (unsigned)b2 | ((unsigned)b3<<16);
  *reinterpret_cast<uint2*>(cb16 + (size_t)c*CDIM + d0) = make_uint2(lo, hi);
  ct16[(size_t)(d0+0)*CNUM + c] = b0;
  ct16[(size_t)(d0+1)*CNUM + c] = b1;
  ct16[(size_t)(d0+2)*CNUM + c] = b2;
  ct16[(size_t)(d0+3)*CNUM + c] = b3;
}

__global__ __launch_bounds__(256) void prep_e2(const float* __restrict__ centers, float* __restrict__ e2){
  int k = blockIdx.x*256 + threadIdx.x;
  const float4* c4 = reinterpret_cast<const float4*>(centers) + (size_t)k*(CDIM/4);
  float s = 0.f;
  #pragma unroll
  for (int i=0;i<CDIM/4;i++){ float4 v = c4[i]; s += dot4(v,v); }
  e2[k] = s;
}

// ---------- K1: GEMM1 (MFMA bf16) + x2 -> sq bf16 TOKEN-MAJOR [tokblk32][t32][1024c] ----------
__global__ __launch_bounds__(512) void k1_gemm1(const float* __restrict__ data,
                                                const unsigned short* __restrict__ cb16,
                                                const float* __restrict__ e2g,
                                                unsigned short* __restrict__ scr16){
  __shared__ unsigned short xb[64*256];
  __shared__ unsigned short cb[64*256];
  __shared__ unsigned short st[64*72];
  __shared__ float e2s[64];
  __shared__ float px[512];
  __shared__ float x2s[64];

  const int tid = threadIdx.x;
  const int w = tid>>6, lane = tid&63;
  const int l15 = lane&15, g = lane>>4;
  const int b = blockIdx.x>>4, hw0 = (blockIdx.x&15)*64;

  {
    float p2 = 0.f;
    const float* dp = data + ((size_t)b*CDIM + 32*w)*1024 + hw0 + lane;
    #pragma unroll
    for (int i=0;i<16;i++){
      int dd = 2*i;
      float v0 = dp[(size_t)dd*1024];
      float v1 = dp[(size_t)(dd+1)*1024];
      p2 += v0*v0 + v1*v1;
      unsigned pk = (unsigned)f2bf(v0) | ((unsigned)f2bf(v1)<<16);
      int d = 32*w + dd;
      int s = d>>3;
      *reinterpret_cast<unsigned*>((char*)xb + lane*512 + (((s ^ (lane&7))<<4)) + (d&7)*2) = pk;
    }
    px[w*64 + lane] = p2;
  }
  __syncthreads();
  if (tid < 64){
    float s = 0.f;
    #pragma unroll
    for (int wv=0; wv<8; wv++) s += px[wv*64 + tid];
    x2s[tid] = s;
  }

  const int tt  = w & 3;
  const int ch2 = w >> 2;
  const int t   = 16*tt + l15;
  const size_t tbase2 = (((size_t)b*1024 + hw0) >> 5) * 32768;

  for (int cc=0; cc<16; cc++){
    __syncthreads();
    #pragma unroll
    for (int it=0; it<4; it++){
      int e = tid + 512*it;
      int c = e>>5, s = e&31;
      uint4 v = *reinterpret_cast<const uint4*>(cb16 + ((size_t)(cc*64 + c))*CDIM + s*8);
      *reinterpret_cast<uint4*>((char*)cb + c*512 + ((s ^ (c&7))<<4)) = v;
    }
    if (tid < 64) e2s[tid] = e2g[cc*64 + tid];
    __syncthreads();

    f32x4 acc0 = {0.f,0.f,0.f,0.f}, acc1 = {0.f,0.f,0.f,0.f};
    const int c0 = 32*ch2 + l15, c1 = c0 + 16;
    #pragma unroll
    for (int k=0;k<8;k++){
      bf16x8 bf = *reinterpret_cast<const bf16x8*>((const char*)xb + t*512 + (((4*k+g) ^ (t&7))<<4));
      bf16x8 a0 = *reinterpret_cast<const bf16x8*>((const char*)cb + c0*512 + (((4*k+g) ^ (c0&7))<<4));
      bf16x8 a1 = *reinterpret_cast<const bf16x8*>((const char*)cb + c1*512 + (((4*k+g) ^ (c1&7))<<4));
      acc0 = __builtin_amdgcn_mfma_f32_16x16x32_bf16(a0, bf, acc0, 0,0,0);
      acc1 = __builtin_amdgcn_mfma_f32_16x16x32_bf16(a1, bf, acc1, 0,0,0);
    }
    float x2v = x2s[t];
    {
      int clA = 32*ch2 + 4*g;
      u16x4 pA, pB;
      #pragma unroll
      for (int r=0;r<4;r++){
        pA[r] = f2bf(x2v - 2.0f*acc0[r] + e2s[clA + r]);
        pB[r] = f2bf(x2v - 2.0f*acc1[r] + e2s[clA + 16 + r]);
      }
      *reinterpret_cast<u16x4*>(&st[t*72 + clA])      = pA;
      *reinterpret_cast<u16x4*>(&st[t*72 + clA + 16]) = pB;
    }
    __syncthreads();
    {
      int tloc = tid>>3, seg = tid&7;
      uint4 v = *reinterpret_cast<const uint4*>(&st[tloc*72 + 8*seg]);
      size_t dst = tbase2 + (size_t)(tloc>>5)*32768 + (size_t)(tloc&31)*1024 + cc*64 + 8*seg;
      *reinterpret_cast<uint4*>(scr16 + dst) = v;
    }
  }
}

// ---------- K2: softmax + exact argmin + outputs; 1024 threads, 32 tokens, single pass ----------
// LDS: S 64KB (sq->phi bf16) + H 16KB. 2 blocks/CU -> 32 waves/CU (8/SIMD).
template<bool FUSE_G2>
__global__ __launch_bounds__(1024, 8) void k2_soft(const float* __restrict__ data,
                                                   const float* __restrict__ centers,
                                                   const unsigned short* __restrict__ ct16,
                                                   const unsigned short* __restrict__ scr16,
                                                   float* __restrict__ out){
  __shared__ unsigned short S[32*1024];   // byte = t*2048 + ((2c) ^ ((t&7)<<4))
  __shared__ unsigned short H[32*256];    // byte = t*512  + ((2d) ^ ((t&7)<<4))

  const int tid = threadIdx.x;            // 0..1023
  const int w = tid>>6, lane = tid&63;
  const int l15 = lane&15, g = lane>>4;
  const int tok0 = blockIdx.x*32;
  const int bb = tok0>>10, hw0 = tok0&1023;
  const unsigned short* sqblk = scr16 + (size_t)blockIdx.x*32768;   // [t32][1024c]

  // ---- P0: bulk sq -> S (vectorized both sides; 4 uint4/thread in flight) ----
  #pragma unroll
  for (int it=0; it<4; it++){
    int e = tid + 1024*it;               // 0..4095: t = e>>7, c8 = e&127
    int t = e>>7, c8 = e&127;
    uint4 v = *reinterpret_cast<const uint4*>(sqblk + t*1024 + 8*c8);
    *reinterpret_cast<uint4*>((char*)S + t*2048 + ((16*c8) ^ ((t&7)<<4))) = v;
  }
  __syncthreads();

  // ---- P1: one token per 32-lane group (32 groups concurrently) ----
  {
    const int t = tid>>5;                // token 0..31
    const int j = tid&31;
    const int hb = (lane>=32)?32:0;
    const int tswz = (t&7)<<4;
    char* srow = (char*)S + t*2048;

    float a[32];
    float mns = 3.4e38f;
    #pragma unroll
    for (int i=0;i<32;i++){
      float sp = bf2f(*(const unsigned short*)(srow + ((2*(j+32*i)) ^ tswz)));
      a[i] = sp;
      mns = fminf(mns, sp);
    }
    #pragma unroll
    for (int m=16;m>=1;m>>=1) mns = fminf(mns, __shfl_xor(mns, m));
    float thr = mns + EPS_CAND;
    unsigned cm = 0;
    #pragma unroll
    for (int i=0;i<32;i++) if (a[i] < thr) cm |= (1u<<i);

    double bestd = 1.0e300; int bestk = CNUM;
    const float* xp = data + (size_t)bb*262144 + hw0 + t;
    for(;;){
      unsigned long long bal = __ballot(cm != 0);
      unsigned half = (lane<32)? (unsigned)(bal & 0xffffffffULL) : (unsigned)(bal>>32);
      if (!half) break;
      int src = __ffs(half)-1;
      unsigned cmsrc = (unsigned)__shfl((int)cm, hb + src);
      int ii = __ffs(cmsrc)-1;
      int k = src + 32*ii;               // lane src owns centers {src, src+32, ...}
      if (j==src) cm &= ~(1u<<ii);
      double acc = 0.0;
      const float* crow = centers + (size_t)k*CDIM;
      #pragma unroll
      for (int q2=0;q2<8;q2++){
        double xv = (double)xp[(size_t)(j+32*q2)*1024];
        double ev = (double)crow[j+32*q2];
        double df = xv-ev; acc = fma(df,df,acc);
      }
      #pragma unroll
      for (int m=16;m>=1;m>>=1) acc += __shfl_xor(acc, m);
      if (acc < bestd || (acc==bestd && k<bestk)){ bestd=acc; bestk=k; }
    }
    if (j==0) out[OFF_SYM + tok0 + t] = (float)bestk;

    float dmn = sqrtf(fmaxf(mns, 0.f));
    float sum = 0.f;
    #pragma unroll
    for (int i=0;i<32;i++){
      float d = sqrtf(fmaxf(a[i], 0.f));
      a[i] = __expf(dmn - d);
      sum += a[i];
    }
    #pragma unroll
    for (int m=16;m>=1;m>>=1) sum += __shfl_xor(sum, m);
    float rs = 1.f/sum;
    #pragma unroll
    for (int i=0;i<32;i++){
      *(unsigned short*)(srow + ((2*(j+32*i)) ^ tswz)) = f2bf(clamp01(a[i]*rs));
    }
    const float* hrow = centers + (size_t)bestk*CDIM;
    #pragma unroll
    for (int q2=0;q2<8;q2++){
      int c = j + 32*q2;
      *(unsigned short*)((char*)H + t*512 + ((2*c) ^ tswz)) = f2bf(hrow[c]);
    }
  }
  __syncthreads();

  // ---- P2a: phi fp32 (blocked 4c x 4t transpose; 8 lanes -> one 128B line) ----
  #pragma unroll
  for (int it2=0; it2<2; ++it2){
    int e = tid + 1024*it2;              // 0..2047: tq = e&7, c4 = e>>3 (0..255)
    int tq = e&7, c4 = e>>3;
    int t0 = 4*tq, c0 = 4*c4;
    float vals[4][4];
    #pragma unroll
    for (int v2=0; v2<4; v2++){
      int t = t0+v2;
      u16x4 r = *reinterpret_cast<const u16x4*>((const char*)S + t*2048 + ((2*c0) ^ ((t&7)<<4)));
      #pragma unroll
      for (int u=0;u<4;u++) vals[u][v2] = bf2f(r[u]);
    }
    #pragma unroll
    for (int u=0;u<4;u++){
      float4 s4 = make_float4(vals[u][0],vals[u][1],vals[u][2],vals[u][3]);
      *reinterpret_cast<float4*>(out + OFF_PHI + (size_t)bb*1048576 + (size_t)(c0+u)*1024 + hw0 + t0) = s4;
    }
  }
  // ---- P2b: zbar (+zhard when fused) (blocked 4d x 4t; threads < 512) ----
  if (tid < 512){
    int tq = tid&7, d4 = tid>>3;         // d4 < 64
    int t0 = 4*tq, d0 = 4*d4;
    float vals[4][4];
    #pragma unroll
    for (int v2=0; v2<4; v2++){
      int t = t0+v2;
      u16x4 r = *reinterpret_cast<const u16x4*>((const char*)H + t*512 + ((2*d0) ^ ((t&7)<<4)));
      #pragma unroll
      for (int u=0;u<4;u++) vals[u][v2] = bf2f(r[u]);
    }
    #pragma unroll
    for (int u=0;u<4;u++){
      float4 s4 = make_float4(vals[u][0],vals[u][1],vals[u][2],vals[u][3]);
      size_t base = (size_t)bb*262144 + (size_t)(d0+u)*1024 + hw0 + t0;
      *reinterpret_cast<float4*>(out + OFF_ZBAR + base) = s4;
      if (FUSE_G2) *reinterpret_cast<float4*>(out + OFF_ZHARD + base) = s4;
    }
  }

  if (FUSE_G2){
    __syncthreads();   // H consumed; S (phi bf16) intact
    // ---- P3: GEMM2: 16 waves, wave w -> dims [16w,16w+16); 64 MFMA/wave ----
    f32x4 z0 = {0.f,0.f,0.f,0.f}, z1 = {0.f,0.f,0.f,0.f};
    const unsigned short* ar = ct16 + (size_t)(16*w + l15)*CNUM;
    const char* br0 = (const char*)S + (size_t)l15*2048;
    const char* br1 = (const char*)S + (size_t)(16+l15)*2048;
    const int bswz = (l15&7)<<4;
    #pragma unroll 8
    for (int s=0;s<32;s++){
      bf16x8 b0 = *reinterpret_cast<const bf16x8*>(br0 + ((64*s + 16*g) ^ bswz));
      bf16x8 b1 = *reinterpret_cast<const bf16x8*>(br1 + ((64*s + 16*g) ^ bswz));
      bf16x8 a0 = *reinterpret_cast<const bf16x8*>(ar + 32*s + 8*g);
      z0 = __builtin_amdgcn_mfma_f32_16x16x32_bf16(a0, b0, z0, 0,0,0);
      z1 = __builtin_amdgcn_mfma_f32_16x16x32_bf16(a0, b1, z1, 0,0,0);
    }
    #pragma unroll
    for (int nt=0;nt<2;nt++){
      f32x4 ac = nt ? z1 : z0;
      int t  = nt*16 + l15;
      int d0 = 16*w + 4*g;
      unsigned w0 = (unsigned)f2bf(clamp11(ac[0])) | ((unsigned)f2bf(clamp11(ac[1]))<<16);
      unsigned w1 = (unsigned)f2bf(clamp11(ac[2])) | ((unsigned)f2bf(clamp11(ac[3]))<<16);
      *reinterpret_cast<uint2*>((char*)H + t*512 + ((2*d0) ^ ((t&7)<<4))) = make_uint2(w0,w1);
    }
    __syncthreads();
    // ---- P4: zsoft stores (blocked 4d x 4t; threads < 512) ----
    if (tid < 512){
      int tq = tid&7, d4 = tid>>3;
      int t0 = 4*tq, d0 = 4*d4;
      float vals[4][4];
      #pragma unroll
      for (int v2=0; v2<4; v2++){
        int t = t0+v2;
        u16x4 r = *reinterpret_cast<const u16x4*>((const char*)H + t*512 + ((2*d0) ^ ((t&7)<<4)));
        #pragma unroll
        for (int u=0;u<4;u++) vals[u][v2] = bf2f(r[u]);
      }
      #pragma unroll
      for (int u=0;u<4;u++){
        float4 s4 = make_float4(vals[u][0],vals[u][1],vals[u][2],vals[u][3]);
        *reinterpret_cast<float4*>(out + OFF_ZSOFT + (size_t)bb*262144 + (size_t)(d0+u)*1024 + hw0 + t0) = s4;
      }
    }
  }
}

// ---------- K3 (fallback only): GEMM2 from phi fp32 (R7-proven) ----------
__global__ __launch_bounds__(512) void k3_gemm2(const float* __restrict__ phi,
                                                const unsigned short* __restrict__ ct16,
                                                float* __restrict__ zsoft){
  __shared__ unsigned short pls[64*64];
  const int tid = threadIdx.x;
  const int w = tid>>6, lane = tid&63;
  const int l15 = lane&15, g = lane>>4;
  const int b = blockIdx.x>>4, hw0 = (blockIdx.x&15)*64;

  f32x4 acc[2][4];
  #pragma unroll
  for (int h=0;h<2;h++)
    #pragma unroll
    for (int t2=0;t2<4;t2++) acc[h][t2] = (f32x4){0.f,0.f,0.f,0.f};

  for (int ks=0; ks<16; ks++){
    int k0s = ks*64;
    __syncthreads();
    #pragma unroll
    for (int it=0; it<4; it++){
      int e = tid + 512*it;
      int kp = e>>6, t = e&63;
      const float* pp = phi + (size_t)b*1048576 + (size_t)(k0s + 2*kp)*1024 + hw0 + t;
      float v0 = pp[0];
      float v1 = pp[1024];
      unsigned pk = (unsigned)f2bf(v0) | ((unsigned)f2bf(v1)<<16);
      int kk = 2*kp;
      int s = kk>>3;
      *reinterpret_cast<unsigned*>((char*)pls + t*128 + ((s ^ (t&7))<<4) + (kk&7)*2) = pk;
    }
    __syncthreads();
    #pragma unroll
    for (int ki=0; ki<2; ki++){
      int kk0 = k0s + 32*ki;
      bf16x8 a0 = *reinterpret_cast<const bf16x8*>(ct16 + (size_t)(32*w + l15)*CNUM + kk0 + 8*g);
      bf16x8 a1 = *reinterpret_cast<const bf16x8*>(ct16 + (size_t)(32*w + 16 + l15)*CNUM + kk0 + 8*g);
      #pragma unroll
      for (int t2=0;t2<4;t2++){
        int t = 16*t2 + l15;
        bf16x8 bf = *reinterpret_cast<const bf16x8*>((const char*)pls + t*128 + (((4*ki+g) ^ (t&7))<<4));
        acc[0][t2] = __builtin_amdgcn_mfma_f32_16x16x32_bf16(a0, bf, acc[0][t2], 0,0,0);
        acc[1][t2] = __builtin_amdgcn_mfma_f32_16x16x32_bf16(a1, bf, acc[1][t2], 0,0,0);
      }
    }
  }
  #pragma unroll
  for (int h=0;h<2;h++)
    #pragma unroll
    for (int t2=0;t2<4;t2++)
      #pragma unroll
      for (int r=0;r<4;r++){
        int d = 32*w + 16*h + 4*g + r;
        zsoft[(size_t)b*262144 + (size_t)d*1024 + hw0 + 16*t2 + l15] = clamp11(acc[h][t2][r]);
      }
}

extern "C" void kernel_launch(void* const* d_in, const int* in_sizes, int n_in,
                              void* d_out, int out_size, void* d_ws, size_t ws_size,
                              hipStream_t stream) {
  const float* data    = (const float*)d_in[0];
  const float* centers = (const float*)d_in[1];
  float* out           = (float*)d_out;

  const size_t SQ_BYTES = (size_t)1024*65536*2;   // 134,217,728
  const bool wsmode = (ws_size >= SQ_BYTES + 524288 + 524288 + 4096);

  unsigned short *scr16, *cb16, *ct16;
  float *e2;
  if (wsmode){
    scr16 = (unsigned short*)d_ws;
    cb16  = (unsigned short*)((char*)d_ws + SQ_BYTES);
    ct16  = (unsigned short*)((char*)d_ws + SQ_BYTES + 524288);
    e2    = (float*)((char*)d_ws + SQ_BYTES + 1048576);
  } else {
    scr16 = (unsigned short*)(out + OFF_ZSOFT);   // zsoft+zhard as scratch
    cb16  = (unsigned short*)d_ws;
    ct16  = (unsigned short*)((char*)d_ws + 524288);
    e2    = (float*)((char*)d_ws + 1048576);
  }

  prep_convert<<<dim3(256), dim3(256), 0, stream>>>(centers, cb16, ct16);
  prep_e2<<<dim3(4), dim3(256), 0, stream>>>(centers, e2);
  k1_gemm1<<<dim3(1024), dim3(512), 0, stream>>>(data, cb16, e2, scr16);
  if (wsmode){
    k2_soft<true><<<dim3(2048), dim3(1024), 0, stream>>>(data, centers, ct16, scr16, out);
  } else {
    k2_soft<false><<<dim3(2048), dim3(1024), 0, stream>>>(data, centers, ct16, scr16, out);
    hipMemcpyAsync(out + OFF_ZHARD, out + OFF_ZBAR, (size_t)16777216*4, hipMemcpyDeviceToDevice, stream);
    k3_gemm2<<<dim3(1024), dim3(512), 0, stream>>>(out + OFF_PHI, ct16, out + OFF_ZSOFT);
  }
}

// Round 19
// 443.027 us; speedup vs baseline: 1.4235x; 1.4235x over previous
//
#include <hip/hip_runtime.h>

#define CNUM 1024
#define CDIM 256
#define EPS_CAND 6.0f

// out region offsets in FP32 elements (zbar, zsoft, zhard, symbols, phisoft)
#define OFF_ZBAR   ((size_t)0)
#define OFF_ZSOFT  ((size_t)16777216)
#define OFF_ZHARD  ((size_t)33554432)
#define OFF_SYM    ((size_t)50331648)
#define OFF_PHI    ((size_t)50397184)

typedef __attribute__((ext_vector_type(8))) short bf16x8;
typedef __attribute__((ext_vector_type(4))) float f32x4;
typedef __attribute__((ext_vector_type(4))) unsigned short u16x4;

__device__ __forceinline__ unsigned short f2bf(float f){
  unsigned u = __float_as_uint(f);
  u += 0x7fffu + ((u >> 16) & 1u);
  return (unsigned short)(u >> 16);
}
__device__ __forceinline__ float bf2f(unsigned short h){
  return __uint_as_float(((unsigned)h) << 16);
}
__device__ __forceinline__ float clamp01(float v){ return fminf(1.0f, fmaxf(0.0f, v)); }
__device__ __forceinline__ float clamp11(float v){ return fminf(1.0f, fmaxf(-1.0f, v)); }
__device__ __forceinline__ float dot4(float4 a, float4 b){ return a.x*b.x + a.y*b.y + a.z*b.z + a.w*b.w; }
__device__ __forceinline__ void nt_store4(float* p, float a, float b, float c, float d){
  f32x4 v = {a,b,c,d};
  __builtin_nontemporal_store(v, reinterpret_cast<f32x4*>(p));
}

// ---------- prep ----------
__global__ __launch_bounds__(256) void prep_convert(const float* __restrict__ centers,
                                                    unsigned short* __restrict__ cb16,
                                                    unsigned short* __restrict__ ct16){
  int gid = blockIdx.x*256 + threadIdx.x;
  int c = gid >> 6, d0 = (gid & 63)*4;
  float4 v = *reinterpret_cast<const float4*>(centers + (size_t)c*CDIM + d0);
  unsigned short b0=f2bf(v.x), b1=f2bf(v.y), b2=f2bf(v.z), b3=f2bf(v.w);
  unsigned lo = (unsigned)b0 | ((unsigned)b1<<16);
  unsigned hi = (unsigned)b2 | ((unsigned)b3<<16);
  *reinterpret_cast<uint2*>(cb16 + (size_t)c*CDIM + d0) = make_uint2(lo, hi);
  ct16[(size_t)(d0+0)*CNUM + c] = b0;
  ct16[(size_t)(d0+1)*CNUM + c] = b1;
  ct16[(size_t)(d0+2)*CNUM + c] = b2;
  ct16[(size_t)(d0+3)*CNUM + c] = b3;
}

__global__ __launch_bounds__(256) void prep_e2(const float* __restrict__ centers, float* __restrict__ e2){
  int k = blockIdx.x*256 + threadIdx.x;
  const float4* c4 = reinterpret_cast<const float4*>(centers) + (size_t)k*(CDIM/4);
  float s = 0.f;
  #pragma unroll
  for (int i=0;i<CDIM/4;i++){ float4 v = c4[i]; s += dot4(v,v); }
  e2[k] = s;
}

// ---------- K1: GEMM1 (MFMA bf16) + x2 -> sq bf16 TOKEN-MAJOR [tokblk32][t32][1024c] ----------
// grid 1024, XCD-chunk swizzled (chunk 128) to align producer XCD with k2's consumer XCD.
__global__ __launch_bounds__(512) void k1_gemm1(const float* __restrict__ data,
                                                const unsigned short* __restrict__ cb16,
                                                const float* __restrict__ e2g,
                                                unsigned short* __restrict__ scr16){
  __shared__ unsigned short xb[64*256];
  __shared__ unsigned short cb[64*256];
  __shared__ unsigned short st[64*72];
  __shared__ float e2s[64];
  __shared__ float px[512];
  __shared__ float x2s[64];

  const int tid = threadIdx.x;
  const int w = tid>>6, lane = tid&63;
  const int l15 = lane&15, g = lane>>4;
  const int sb = (blockIdx.x & 7)*128 + (blockIdx.x >> 3);   // XCD-chunked, bijective (1024 % 8 == 0)
  const int b = sb>>4, hw0 = (sb&15)*64;

  {
    float p2 = 0.f;
    const float* dp = data + ((size_t)b*CDIM + 32*w)*1024 + hw0 + lane;
    #pragma unroll
    for (int i=0;i<16;i++){
      int dd = 2*i;
      float v0 = dp[(size_t)dd*1024];
      float v1 = dp[(size_t)(dd+1)*1024];
      p2 += v0*v0 + v1*v1;
      unsigned pk = (unsigned)f2bf(v0) | ((unsigned)f2bf(v1)<<16);
      int d = 32*w + dd;
      int s = d>>3;
      *reinterpret_cast<unsigned*>((char*)xb + lane*512 + (((s ^ (lane&7))<<4)) + (d&7)*2) = pk;
    }
    px[w*64 + lane] = p2;
  }
  __syncthreads();
  if (tid < 64){
    float s = 0.f;
    #pragma unroll
    for (int wv=0; wv<8; wv++) s += px[wv*64 + tid];
    x2s[tid] = s;
  }

  const int tt  = w & 3;
  const int ch2 = w >> 2;
  const int t   = 16*tt + l15;
  const size_t tbase2 = (((size_t)b*1024 + hw0) >> 5) * 32768;

  for (int cc=0; cc<16; cc++){
    __syncthreads();
    #pragma unroll
    for (int it=0; it<4; it++){
      int e = tid + 512*it;
      int c = e>>5, s = e&31;
      uint4 v = *reinterpret_cast<const uint4*>(cb16 + ((size_t)(cc*64 + c))*CDIM + s*8);
      *reinterpret_cast<uint4*>((char*)cb + c*512 + ((s ^ (c&7))<<4)) = v;
    }
    if (tid < 64) e2s[tid] = e2g[cc*64 + tid];
    __syncthreads();

    f32x4 acc0 = {0.f,0.f,0.f,0.f}, acc1 = {0.f,0.f,0.f,0.f};
    const int c0 = 32*ch2 + l15, c1 = c0 + 16;
    #pragma unroll
    for (int k=0;k<8;k++){
      bf16x8 bf = *reinterpret_cast<const bf16x8*>((const char*)xb + t*512 + (((4*k+g) ^ (t&7))<<4));
      bf16x8 a0 = *reinterpret_cast<const bf16x8*>((const char*)cb + c0*512 + (((4*k+g) ^ (c0&7))<<4));
      bf16x8 a1 = *reinterpret_cast<const bf16x8*>((const char*)cb + c1*512 + (((4*k+g) ^ (c1&7))<<4));
      acc0 = __builtin_amdgcn_mfma_f32_16x16x32_bf16(a0, bf, acc0, 0,0,0);
      acc1 = __builtin_amdgcn_mfma_f32_16x16x32_bf16(a1, bf, acc1, 0,0,0);
    }
    float x2v = x2s[t];
    {
      int clA = 32*ch2 + 4*g;
      u16x4 pA, pB;
      #pragma unroll
      for (int r=0;r<4;r++){
        pA[r] = f2bf(x2v - 2.0f*acc0[r] + e2s[clA + r]);
        pB[r] = f2bf(x2v - 2.0f*acc1[r] + e2s[clA + 16 + r]);
      }
      *reinterpret_cast<u16x4*>(&st[t*72 + clA])      = pA;
      *reinterpret_cast<u16x4*>(&st[t*72 + clA + 16]) = pB;
    }
    __syncthreads();
    {
      int tloc = tid>>3, seg = tid&7;
      uint4 v = *reinterpret_cast<const uint4*>(&st[tloc*72 + 8*seg]);
      size_t dst = tbase2 + (size_t)(tloc>>5)*32768 + (size_t)(tloc&31)*1024 + cc*64 + 8*seg;
      *reinterpret_cast<uint4*>(scr16 + dst) = v;
    }
  }
}

// ---------- K2: softmax + exact argmin + outputs. FUSE_G2: + zhard + in-block GEMM2 ----------
// 32 tokens/block, 512 threads, grid 2048 XCD-chunk swizzled (chunk 256). LDS 80 KB, 2 blocks/CU.
// Final fp32 outputs stored non-temporally (streaming, never re-read).
template<bool FUSE_G2>
__global__ __launch_bounds__(512, 4) void k2_soft(const float* __restrict__ data,
                                                  const float* __restrict__ centers,
                                                  const unsigned short* __restrict__ ct16,
                                                  const unsigned short* __restrict__ scr16,
                                                  float* __restrict__ out){
  __shared__ unsigned short S[32*1024];   // sq bf16 -> phi bf16; byte = t*2048 + ((2c) ^ ((t&7)<<4))
  __shared__ unsigned short H[32*256];    // hard bf16 (-> zsoft bf16); byte = t*512 + ((2d) ^ ((t&7)<<4))

  const int tid = threadIdx.x;
  const int w = tid>>6, lane = tid&63;
  const int l15 = lane&15, g = lane>>4;
  const int sb = (blockIdx.x & 7)*256 + (blockIdx.x >> 3);   // same XCD gets same token range as k1
  const int tok0 = sb*32;
  const int bb = tok0>>10, hw0 = tok0&1023;
  const unsigned short* sqblk = scr16 + (size_t)sb*32768;    // contiguous 64KB, XCD-local

  // ---- P0: read sq bf16 [t32][1024c] -> S (transposed to per-token rows, swizzled) ----
  #pragma unroll
  for (int it=0; it<8; it++){
    int e = tid + 512*it;              // 0..4095: t = e>>7, c8 = e&127
    int t = e>>7, c8 = e&127;
    uint4 v = *reinterpret_cast<const uint4*>(sqblk + t*1024 + 8*c8);
    *reinterpret_cast<uint4*>((char*)S + t*2048 + ((16*c8) ^ ((t&7)<<4))) = v;
  }
  __syncthreads();

  // ---- P1: two passes of 16 tokens: softmax + fp64-refined argmin ----
  for (int p=0;p<2;p++){
    const int t = p*16 + (tid>>5);
    const int j = tid&31;
    const int hb = (lane>=32)?32:0;
    const int tswz = (t&7)<<4;
    char* srow = (char*)S + t*2048;

    float a[32];
    float mns = 3.4e38f;
    #pragma unroll
    for (int i=0;i<32;i++){
      float sp = bf2f(*(const unsigned short*)(srow + ((2*(j+32*i)) ^ tswz)));
      a[i] = sp;
      mns = fminf(mns, sp);
    }
    #pragma unroll
    for (int m=16;m>=1;m>>=1) mns = fminf(mns, __shfl_xor(mns, m));
    float thr = mns + EPS_CAND;
    unsigned cm = 0;
    #pragma unroll
    for (int i=0;i<32;i++) if (a[i] < thr) cm |= (1u<<i);

    double bestd = 1.0e300; int bestk = CNUM;
    const float* xp = data + (size_t)bb*262144 + hw0 + t;
    for(;;){
      unsigned long long bal = __ballot(cm != 0);
      unsigned half = (lane<32)? (unsigned)(bal & 0xffffffffULL) : (unsigned)(bal>>32);
      if (!half) break;
      int src = __ffs(half)-1;
      unsigned cmsrc = (unsigned)__shfl((int)cm, hb + src);
      int ii = __ffs(cmsrc)-1;
      int k = src + 32*ii;               // lane src owns centers {src, src+32, ...}
      if (j==src) cm &= ~(1u<<ii);
      double acc = 0.0;
      const float* crow = centers + (size_t)k*CDIM;
      #pragma unroll
      for (int q2=0;q2<8;q2++){
        double xv = (double)xp[(size_t)(j+32*q2)*1024];
        double ev = (double)crow[j+32*q2];
        double df = xv-ev; acc = fma(df,df,acc);
      }
      #pragma unroll
      for (int m=16;m>=1;m>>=1) acc += __shfl_xor(acc, m);
      if (acc < bestd || (acc==bestd && k<bestk)){ bestd=acc; bestk=k; }
    }
    if (j==0) out[OFF_SYM + tok0 + t] = (float)bestk;

    float dmn = sqrtf(fmaxf(mns, 0.f));
    float sum = 0.f;
    #pragma unroll
    for (int i=0;i<32;i++){
      float d = sqrtf(fmaxf(a[i], 0.f));
      a[i] = __expf(dmn - d);
      sum += a[i];
    }
    #pragma unroll
    for (int m=16;m>=1;m>>=1) sum += __shfl_xor(sum, m);
    float rs = 1.f/sum;
    #pragma unroll
    for (int i=0;i<32;i++){
      *(unsigned short*)(srow + ((2*(j+32*i)) ^ tswz)) = f2bf(clamp01(a[i]*rs));
    }
    const float* hrow = centers + (size_t)bestk*CDIM;
    #pragma unroll
    for (int q2=0;q2<8;q2++){
      int c = j + 32*q2;
      *(unsigned short*)((char*)H + t*512 + ((2*c) ^ tswz)) = f2bf(hrow[c]);
    }
  }
  __syncthreads();

  // ---- P2a: phi fp32 stores (full 128B line, non-temporal) ----
  #pragma unroll
  for (int it=0; it<16; ++it){
    int e = tid + 512*it;              // c = e>>3, q = e&7
    int c = e>>3, q = e&7;
    float vv[4];
    #pragma unroll
    for (int u=0;u<4;u++){
      int t = 4*q + u;
      vv[u] = bf2f(*(const unsigned short*)((const char*)S + t*2048 + ((2*c) ^ ((t&7)<<4))));
    }
    nt_store4(out + OFF_PHI + (size_t)bb*1048576 + (size_t)c*1024 + hw0 + 4*q,
              vv[0], vv[1], vv[2], vv[3]);
  }
  // ---- P2b: zbar (+zhard when fused) stores (full 128B line, non-temporal) ----
  #pragma unroll
  for (int it=0; it<4; ++it){
    int e = tid + 512*it;              // d = e>>3, q = e&7
    int d = e>>3, q = e&7;
    float vv[4];
    #pragma unroll
    for (int u=0;u<4;u++){
      int t = 4*q + u;
      vv[u] = bf2f(*(const unsigned short*)((const char*)H + t*512 + ((2*d) ^ ((t&7)<<4))));
    }
    size_t base = (size_t)bb*262144 + (size_t)d*1024 + hw0 + 4*q;
    nt_store4(out + OFF_ZBAR + base, vv[0], vv[1], vv[2], vv[3]);
    if (FUSE_G2) nt_store4(out + OFF_ZHARD + base, vv[0], vv[1], vv[2], vv[3]);
  }

  if (FUSE_G2){
    __syncthreads();   // H consumed; S (phi bf16) still intact
    // ---- P3: GEMM2: zsoft^T = ct16 . phi^T (B-frags from S) ----
    f32x4 z00={0.f,0.f,0.f,0.f}, z01=z00, z10=z00, z11=z00;
    const unsigned short* ar0 = ct16 + (size_t)(16*w + l15)*CNUM;
    const unsigned short* ar1 = ct16 + (size_t)(16*(w+8) + l15)*CNUM;
    const char* br0 = (const char*)S + (size_t)l15*2048;
    const char* br1 = (const char*)S + (size_t)(16+l15)*2048;
    const int bswz = (l15&7)<<4;
    #pragma unroll 8
    for (int s=0;s<32;s++){
      bf16x8 b0 = *reinterpret_cast<const bf16x8*>(br0 + ((64*s + 16*g) ^ bswz));
      bf16x8 b1 = *reinterpret_cast<const bf16x8*>(br1 + ((64*s + 16*g) ^ bswz));
      bf16x8 a0 = *reinterpret_cast<const bf16x8*>(ar0 + 32*s + 8*g);
      bf16x8 a1 = *reinterpret_cast<const bf16x8*>(ar1 + 32*s + 8*g);
      z00 = __builtin_amdgcn_mfma_f32_16x16x32_bf16(a0, b0, z00, 0,0,0);
      z01 = __builtin_amdgcn_mfma_f32_16x16x32_bf16(a0, b1, z01, 0,0,0);
      z10 = __builtin_amdgcn_mfma_f32_16x16x32_bf16(a1, b0, z10, 0,0,0);
      z11 = __builtin_amdgcn_mfma_f32_16x16x32_bf16(a1, b1, z11, 0,0,0);
    }
    #pragma unroll
    for (int mi=0;mi<2;mi++){
      #pragma unroll
      for (int nt=0;nt<2;nt++){
        f32x4 ac = (mi==0) ? (nt==0 ? z00 : z01) : (nt==0 ? z10 : z11);
        int mt = w + 8*mi;
        int t  = nt*16 + l15;
        int d0 = 16*mt + 4*g;
        unsigned w0 = (unsigned)f2bf(clamp11(ac[0])) | ((unsigned)f2bf(clamp11(ac[1]))<<16);
        unsigned w1 = (unsigned)f2bf(clamp11(ac[2])) | ((unsigned)f2bf(clamp11(ac[3]))<<16);
        *reinterpret_cast<uint2*>((char*)H + t*512 + ((2*d0) ^ ((t&7)<<4))) = make_uint2(w0,w1);
      }
    }
    __syncthreads();
    // ---- P4: zsoft stores (full 128B line, non-temporal) ----
    #pragma unroll
    for (int it=0; it<4; ++it){
      int e = tid + 512*it;
      int d = e>>3, q = e&7;
      float vv[4];
      #pragma unroll
      for (int u=0;u<4;u++){
        int t = 4*q + u;
        vv[u] = bf2f(*(const unsigned short*)((const char*)H + t*512 + ((2*d) ^ ((t&7)<<4))));
      }
      nt_store4(out + OFF_ZSOFT + (size_t)bb*262144 + (size_t)d*1024 + hw0 + 4*q,
                vv[0], vv[1], vv[2], vv[3]);
    }
  }
}

// ---------- K3 (fallback only): GEMM2 from phi fp32 (R7-proven) ----------
__global__ __launch_bounds__(512) void k3_gemm2(const float* __restrict__ phi,
                                                const unsigned short* __restrict__ ct16,
                                                float* __restrict__ zsoft){
  __shared__ unsigned short pls[64*64];
  const int tid = threadIdx.x;
  const int w = tid>>6, lane = tid&63;
  const int l15 = lane&15, g = lane>>4;
  const int b = blockIdx.x>>4, hw0 = (blockIdx.x&15)*64;

  f32x4 acc[2][4];
  #pragma unroll
  for (int h=0;h<2;h++)
    #pragma unroll
    for (int t2=0;t2<4;t2++) acc[h][t2] = (f32x4){0.f,0.f,0.f,0.f};

  for (int ks=0; ks<16; ks++){
    int k0s = ks*64;
    __syncthreads();
    #pragma unroll
    for (int it=0; it<4; it++){
      int e = tid + 512*it;
      int kp = e>>6, t = e&63;
      const float* pp = phi + (size_t)b*1048576 + (size_t)(k0s + 2*kp)*1024 + hw0 + t;
      float v0 = pp[0];
      float v1 = pp[1024];
      unsigned pk = (unsigned)f2bf(v0) | ((unsigned)f2bf(v1)<<16);
      int kk = 2*kp;
      int s = kk>>3;
      *reinterpret_cast<unsigned*>((char*)pls + t*128 + ((s ^ (t&7))<<4) + (kk&7)*2) = pk;
    }
    __syncthreads();
    #pragma unroll
    for (int ki=0; ki<2; ki++){
      int kk0 = k0s + 32*ki;
      bf16x8 a0 = *reinterpret_cast<const bf16x8*>(ct16 + (size_t)(32*w + l15)*CNUM + kk0 + 8*g);
      bf16x8 a1 = *reinterpret_cast<const bf16x8*>(ct16 + (size_t)(32*w + 16 + l15)*CNUM + kk0 + 8*g);
      #pragma unroll
      for (int t2=0;t2<4;t2++){
        int t = 16*t2 + l15;
        bf16x8 bf = *reinterpret_cast<const bf16x8*>((const char*)pls + t*128 + (((4*ki+g) ^ (t&7))<<4));
        acc[0][t2] = __builtin_amdgcn_mfma_f32_16x16x32_bf16(a0, bf, acc[0][t2], 0,0,0);
        acc[1][t2] = __builtin_amdgcn_mfma_f32_16x16x32_bf16(a1, bf, acc[1][t2], 0,0,0);
      }
    }
  }
  #pragma unroll
  for (int h=0;h<2;h++)
    #pragma unroll
    for (int t2=0;t2<4;t2++)
      #pragma unroll
      for (int r=0;r<4;r++){
        int d = 32*w + 16*h + 4*g + r;
        zsoft[(size_t)b*262144 + (size_t)d*1024 + hw0 + 16*t2 + l15] = clamp11(acc[h][t2][r]);
      }
}

extern "C" void kernel_launch(void* const* d_in, const int* in_sizes, int n_in,
                              void* d_out, int out_size, void* d_ws, size_t ws_size,
                              hipStream_t stream) {
  const float* data    = (const float*)d_in[0];
  const float* centers = (const float*)d_in[1];
  float* out           = (float*)d_out;

  const size_t SQ_BYTES = (size_t)1024*65536*2;   // 134,217,728
  const bool wsmode = (ws_size >= SQ_BYTES + 524288 + 524288 + 4096);

  unsigned short *scr16, *cb16, *ct16;
  float *e2;
  if (wsmode){
    scr16 = (unsigned short*)d_ws;
    cb16  = (unsigned short*)((char*)d_ws + SQ_BYTES);
    ct16  = (unsigned short*)((char*)d_ws + SQ_BYTES + 524288);
    e2    = (float*)((char*)d_ws + SQ_BYTES + 1048576);
  } else {
    scr16 = (unsigned short*)(out + OFF_ZSOFT);   // zsoft+zhard as scratch
    cb16  = (unsigned short*)d_ws;
    ct16  = (unsigned short*)((char*)d_ws + 524288);
    e2    = (float*)((char*)d_ws + 1048576);
  }

  prep_convert<<<dim3(256), dim3(256), 0, stream>>>(centers, cb16, ct16);
  prep_e2<<<dim3(4), dim3(256), 0, stream>>>(centers, e2);
  k1_gemm1<<<dim3(1024), dim3(512), 0, stream>>>(data, cb16, e2, scr16);
  if (wsmode){
    k2_soft<true><<<dim3(2048), dim3(512), 0, stream>>>(data, centers, ct16, scr16, out);
  } else {
    k2_soft<false><<<dim3(2048), dim3(512), 0, stream>>>(data, centers, ct16, scr16, out);
    hipMemcpyAsync(out + OFF_ZHARD, out + OFF_ZBAR, (size_t)16777216*4, hipMemcpyDeviceToDevice, stream);
    k3_gemm2<<<dim3(1024), dim3(512), 0, stream>>>(out + OFF_PHI, ct16, out + OFF_ZSOFT);
  }
}

// Round 20
// 404.167 us; speedup vs baseline: 1.5604x; 1.0962x over previous
//
#include <hip/hip_runtime.h>

#define CNUM 1024
#define CDIM 256
#define EPS_CAND 6.0f

// out region offsets in FP32 elements (zbar, zsoft, zhard, symbols, phisoft)
#define OFF_ZBAR   ((size_t)0)
#define OFF_ZSOFT  ((size_t)16777216)
#define OFF_ZHARD  ((size_t)33554432)
#define OFF_SYM    ((size_t)50331648)
#define OFF_PHI    ((size_t)50397184)

typedef __attribute__((ext_vector_type(8))) short bf16x8;
typedef __attribute__((ext_vector_type(4))) float f32x4;
typedef __attribute__((ext_vector_type(4))) unsigned short u16x4;

__device__ __forceinline__ unsigned short f2bf(float f){
  unsigned u = __float_as_uint(f);
  u += 0x7fffu + ((u >> 16) & 1u);
  return (unsigned short)(u >> 16);
}
__device__ __forceinline__ float bf2f(unsigned short h){
  return __uint_as_float(((unsigned)h) << 16);
}
__device__ __forceinline__ float clamp01(float v){ return fminf(1.0f, fmaxf(0.0f, v)); }
__device__ __forceinline__ float clamp11(float v){ return fminf(1.0f, fmaxf(-1.0f, v)); }
__device__ __forceinline__ float dot4(float4 a, float4 b){ return a.x*b.x + a.y*b.y + a.z*b.z + a.w*b.w; }
__device__ __forceinline__ void nt_store4(float* p, float a, float b, float c, float d){
  f32x4 v = {a,b,c,d};
  __builtin_nontemporal_store(v, reinterpret_cast<f32x4*>(p));
}

// ---------- prep ----------
__global__ __launch_bounds__(256) void prep_convert(const float* __restrict__ centers,
                                                    unsigned short* __restrict__ cb16,
                                                    unsigned short* __restrict__ ct16){
  int gid = blockIdx.x*256 + threadIdx.x;
  int c = gid >> 6, d0 = (gid & 63)*4;
  float4 v = *reinterpret_cast<const float4*>(centers + (size_t)c*CDIM + d0);
  unsigned short b0=f2bf(v.x), b1=f2bf(v.y), b2=f2bf(v.z), b3=f2bf(v.w);
  unsigned lo = (unsigned)b0 | ((unsigned)b1<<16);
  unsigned hi = (unsigned)b2 | ((unsigned)b3<<16);
  *reinterpret_cast<uint2*>(cb16 + (size_t)c*CDIM + d0) = make_uint2(lo, hi);
  ct16[(size_t)(d0+0)*CNUM + c] = b0;
  ct16[(size_t)(d0+1)*CNUM + c] = b1;
  ct16[(size_t)(d0+2)*CNUM + c] = b2;
  ct16[(size_t)(d0+3)*CNUM + c] = b3;
}

__global__ __launch_bounds__(256) void prep_e2(const float* __restrict__ centers, float* __restrict__ e2){
  int k = blockIdx.x*256 + threadIdx.x;
  const float4* c4 = reinterpret_cast<const float4*>(centers) + (size_t)k*(CDIM/4);
  float s = 0.f;
  #pragma unroll
  for (int i=0;i<CDIM/4;i++){ float4 v = c4[i]; s += dot4(v,v); }
  e2[k] = s;
}

// ---------- K1: GEMM1 (MFMA bf16) + x2 -> sq bf16 TOKEN-MAJOR [tokblk32][t32][1024c] ----------
__global__ __launch_bounds__(512) void k1_gemm1(const float* __restrict__ data,
                                                const unsigned short* __restrict__ cb16,
                                                const float* __restrict__ e2g,
                                                unsigned short* __restrict__ scr16){
  __shared__ unsigned short xb[64*256];
  __shared__ unsigned short cb[64*256];
  __shared__ unsigned short st[64*72];
  __shared__ float e2s[64];
  __shared__ float px[512];
  __shared__ float x2s[64];

  const int tid = threadIdx.x;
  const int w = tid>>6, lane = tid&63;
  const int l15 = lane&15, g = lane>>4;
  const int sb = (blockIdx.x & 7)*128 + (blockIdx.x >> 3);
  const int b = sb>>4, hw0 = (sb&15)*64;

  {
    float p2 = 0.f;
    const float* dp = data + ((size_t)b*CDIM + 32*w)*1024 + hw0 + lane;
    #pragma unroll
    for (int i=0;i<16;i++){
      int dd = 2*i;
      float v0 = dp[(size_t)dd*1024];
      float v1 = dp[(size_t)(dd+1)*1024];
      p2 += v0*v0 + v1*v1;
      unsigned pk = (unsigned)f2bf(v0) | ((unsigned)f2bf(v1)<<16);
      int d = 32*w + dd;
      int s = d>>3;
      *reinterpret_cast<unsigned*>((char*)xb + lane*512 + (((s ^ (lane&7))<<4)) + (d&7)*2) = pk;
    }
    px[w*64 + lane] = p2;
  }
  __syncthreads();
  if (tid < 64){
    float s = 0.f;
    #pragma unroll
    for (int wv=0; wv<8; wv++) s += px[wv*64 + tid];
    x2s[tid] = s;
  }

  const int tt  = w & 3;
  const int ch2 = w >> 2;
  const int t   = 16*tt + l15;
  const size_t tbase2 = (((size_t)b*1024 + hw0) >> 5) * 32768;

  for (int cc=0; cc<16; cc++){
    __syncthreads();
    #pragma unroll
    for (int it=0; it<4; it++){
      int e = tid + 512*it;
      int c = e>>5, s = e&31;
      uint4 v = *reinterpret_cast<const uint4*>(cb16 + ((size_t)(cc*64 + c))*CDIM + s*8);
      *reinterpret_cast<uint4*>((char*)cb + c*512 + ((s ^ (c&7))<<4)) = v;
    }
    if (tid < 64) e2s[tid] = e2g[cc*64 + tid];
    __syncthreads();

    f32x4 acc0 = {0.f,0.f,0.f,0.f}, acc1 = {0.f,0.f,0.f,0.f};
    const int c0 = 32*ch2 + l15, c1 = c0 + 16;
    #pragma unroll
    for (int k=0;k<8;k++){
      bf16x8 bf = *reinterpret_cast<const bf16x8*>((const char*)xb + t*512 + (((4*k+g) ^ (t&7))<<4));
      bf16x8 a0 = *reinterpret_cast<const bf16x8*>((const char*)cb + c0*512 + (((4*k+g) ^ (c0&7))<<4));
      bf16x8 a1 = *reinterpret_cast<const bf16x8*>((const char*)cb + c1*512 + (((4*k+g) ^ (c1&7))<<4));
      acc0 = __builtin_amdgcn_mfma_f32_16x16x32_bf16(a0, bf, acc0, 0,0,0);
      acc1 = __builtin_amdgcn_mfma_f32_16x16x32_bf16(a1, bf, acc1, 0,0,0);
    }
    float x2v = x2s[t];
    {
      int clA = 32*ch2 + 4*g;
      u16x4 pA, pB;
      #pragma unroll
      for (int r=0;r<4;r++){
        pA[r] = f2bf(x2v - 2.0f*acc0[r] + e2s[clA + r]);
        pB[r] = f2bf(x2v - 2.0f*acc1[r] + e2s[clA + 16 + r]);
      }
      *reinterpret_cast<u16x4*>(&st[t*72 + clA])      = pA;
      *reinterpret_cast<u16x4*>(&st[t*72 + clA + 16]) = pB;
    }
    __syncthreads();
    {
      int tloc = tid>>3, seg = tid&7;
      uint4 v = *reinterpret_cast<const uint4*>(&st[tloc*72 + 8*seg]);
      size_t dst = tbase2 + (size_t)(tloc>>5)*32768 + (size_t)(tloc&31)*1024 + cc*64 + 8*seg;
      *reinterpret_cast<uint4*>(scr16 + dst) = v;
    }
  }
}

// ---------- K_A (wsmode): softmax + exact argmin; LDS-free, high occupancy ----------
// 256 threads = 8 tokens/block, grid 8192 XCD-swizzled. Reads sq bf16, overwrites phi bf16 in place.
__global__ __launch_bounds__(256) void ka_soft(const float* __restrict__ data,
                                               const float* __restrict__ centers,
                                               unsigned short* __restrict__ scr16,
                                               float* __restrict__ symout){
  const int tid = threadIdx.x;
  const int lane = tid&63;
  const int j = tid&31;
  const int hb = (lane>=32)?32:0;
  const int sb = (blockIdx.x & 7)*1024 + (blockIdx.x >> 3);   // 8192 % 8 == 0, bijective
  const int tok = sb*8 + (tid>>5);
  const int bb = tok>>10, hw = tok&1023;

  unsigned short* srow = scr16 + (size_t)(tok>>5)*32768 + (size_t)(tok&31)*1024;

  // lane j owns c = 256k + 8j + u  (i = 8k+u)
  float a[32];
  #pragma unroll
  for (int k=0;k<4;k++){
    uint4 v = *reinterpret_cast<const uint4*>(srow + 256*k + 8*j);
    const unsigned short* p = (const unsigned short*)&v;
    #pragma unroll
    for (int u=0;u<8;u++) a[8*k+u] = bf2f(p[u]);
  }
  float mns = 3.4e38f;
  #pragma unroll
  for (int i=0;i<32;i++) mns = fminf(mns, a[i]);
  #pragma unroll
  for (int m=16;m>=1;m>>=1) mns = fminf(mns, __shfl_xor(mns, m));
  float thr = mns + EPS_CAND;
  unsigned cm = 0;
  #pragma unroll
  for (int i=0;i<32;i++) if (a[i] < thr) cm |= (1u<<i);

  double bestd = 1.0e300; int bestk = CNUM;
  const float* xp = data + (size_t)bb*262144 + hw;
  for(;;){
    unsigned long long bal = __ballot(cm != 0);
    unsigned half = (lane<32)? (unsigned)(bal & 0xffffffffULL) : (unsigned)(bal>>32);
    if (!half) break;
    int src = __ffs(half)-1;
    unsigned cmsrc = (unsigned)__shfl((int)cm, hb + src);
    int ii = __ffs(cmsrc)-1;
    int k = 256*(ii>>3) + 8*src + (ii&7);
    if (j==src) cm &= ~(1u<<ii);
    double acc = 0.0;
    const float* crow = centers + (size_t)k*CDIM;
    #pragma unroll
    for (int q2=0;q2<8;q2++){
      double xv = (double)xp[(size_t)(j+32*q2)*1024];
      double ev = (double)crow[j+32*q2];
      double df = xv-ev; acc = fma(df,df,acc);
    }
    #pragma unroll
    for (int m=16;m>=1;m>>=1) acc += __shfl_xor(acc, m);
    if (acc < bestd || (acc==bestd && k<bestk)){ bestd=acc; bestk=k; }
  }
  if (j==0) symout[tok] = (float)bestk;

  float dmn = sqrtf(fmaxf(mns, 0.f));
  float sum = 0.f;
  #pragma unroll
  for (int i=0;i<32;i++){
    float d = sqrtf(fmaxf(a[i], 0.f));
    a[i] = __expf(dmn - d);
    sum += a[i];
  }
  #pragma unroll
  for (int m=16;m>=1;m>>=1) sum += __shfl_xor(sum, m);
  float rs = 1.f/sum;
  // overwrite phi bf16 in place (same addresses as the read -> L2-hot)
  #pragma unroll
  for (int k=0;k<4;k++){
    unsigned w0 = (unsigned)f2bf(clamp01(a[8*k+0]*rs)) | ((unsigned)f2bf(clamp01(a[8*k+1]*rs))<<16);
    unsigned w1 = (unsigned)f2bf(clamp01(a[8*k+2]*rs)) | ((unsigned)f2bf(clamp01(a[8*k+3]*rs))<<16);
    unsigned w2 = (unsigned)f2bf(clamp01(a[8*k+4]*rs)) | ((unsigned)f2bf(clamp01(a[8*k+5]*rs))<<16);
    unsigned w3 = (unsigned)f2bf(clamp01(a[8*k+6]*rs)) | ((unsigned)f2bf(clamp01(a[8*k+7]*rs))<<16);
    *reinterpret_cast<uint4*>(srow + 256*k + 8*j) = make_uint4(w0,w1,w2,w3);
  }
}

// ---------- K_B (wsmode): emission + GEMM2; streaming + MFMA only ----------
// 32 tokens/block, 512 threads, grid 2048 XCD-swizzled. LDS 80 KB.
__global__ __launch_bounds__(512, 4) void kb_emit(const float* __restrict__ centers,
                                                  const unsigned short* __restrict__ ct16,
                                                  const unsigned short* __restrict__ scr16,
                                                  float* __restrict__ out){
  __shared__ unsigned short S[32*1024];   // phi bf16; byte = t*2048 + ((2c) ^ ((t&7)<<4))
  __shared__ unsigned short H[32*256];    // hard bf16 -> zsoft bf16; byte = t*512 + ((2d) ^ ((t&7)<<4))

  const int tid = threadIdx.x;
  const int w = tid>>6, lane = tid&63;
  const int l15 = lane&15, g = lane>>4;
  const int sb = (blockIdx.x & 7)*256 + (blockIdx.x >> 3);
  const int tok0 = sb*32;
  const int bb = tok0>>10, hw0 = tok0&1023;
  const unsigned short* sqblk = scr16 + (size_t)sb*32768;

  // ---- P0: phi bf16 -> S (vectorized, swizzled) ----
  #pragma unroll
  for (int it=0; it<8; it++){
    int e = tid + 512*it;              // t = e>>7, c8 = e&127
    int t = e>>7, c8 = e&127;
    uint4 v = *reinterpret_cast<const uint4*>(sqblk + t*1024 + 8*c8);
    *reinterpret_cast<uint4*>((char*)S + t*2048 + ((16*c8) ^ ((t&7)<<4))) = v;
  }
  // ---- hard-row gather -> H (vectorized; lane j owns d in [8j,8j+8)) ----
  for (int p=0;p<2;p++){
    const int t = p*16 + (tid>>5);
    const int j = tid&31;
    const int tswz = (t&7)<<4;
    int sym = (int)out[OFF_SYM + tok0 + t];
    sym = (sym < 0) ? 0 : (sym > 1023 ? 1023 : sym);
    const float* hrow = centers + (size_t)sym*CDIM + 8*j;
    float4 h0 = *reinterpret_cast<const float4*>(hrow);
    float4 h1 = *reinterpret_cast<const float4*>(hrow+4);
    unsigned w0 = (unsigned)f2bf(h0.x) | ((unsigned)f2bf(h0.y)<<16);
    unsigned w1 = (unsigned)f2bf(h0.z) | ((unsigned)f2bf(h0.w)<<16);
    unsigned w2 = (unsigned)f2bf(h1.x) | ((unsigned)f2bf(h1.y)<<16);
    unsigned w3 = (unsigned)f2bf(h1.z) | ((unsigned)f2bf(h1.w)<<16);
    *reinterpret_cast<uint4*>((char*)H + t*512 + ((16*j) ^ tswz)) = make_uint4(w0,w1,w2,w3);
  }
  __syncthreads();

  // ---- P2a: phi fp32 stores (full 128B line, non-temporal) ----
  #pragma unroll
  for (int it=0; it<16; ++it){
    int e = tid + 512*it;              // c = e>>3, q = e&7
    int c = e>>3, q = e&7;
    float vv[4];
    #pragma unroll
    for (int u=0;u<4;u++){
      int t = 4*q + u;
      vv[u] = bf2f(*(const unsigned short*)((const char*)S + t*2048 + ((2*c) ^ ((t&7)<<4))));
    }
    nt_store4(out + OFF_PHI + (size_t)bb*1048576 + (size_t)c*1024 + hw0 + 4*q,
              vv[0], vv[1], vv[2], vv[3]);
  }
  // ---- P2b: zbar + zhard stores ----
  #pragma unroll
  for (int it=0; it<4; ++it){
    int e = tid + 512*it;              // d = e>>3, q = e&7
    int d = e>>3, q = e&7;
    float vv[4];
    #pragma unroll
    for (int u=0;u<4;u++){
      int t = 4*q + u;
      vv[u] = bf2f(*(const unsigned short*)((const char*)H + t*512 + ((2*d) ^ ((t&7)<<4))));
    }
    size_t base = (size_t)bb*262144 + (size_t)d*1024 + hw0 + 4*q;
    nt_store4(out + OFF_ZBAR + base, vv[0], vv[1], vv[2], vv[3]);
    nt_store4(out + OFF_ZHARD + base, vv[0], vv[1], vv[2], vv[3]);
  }
  __syncthreads();   // H consumed; S intact

  // ---- P3: GEMM2: zsoft^T = ct16 . phi^T ----
  {
    f32x4 z00={0.f,0.f,0.f,0.f}, z01=z00, z10=z00, z11=z00;
    const unsigned short* ar0 = ct16 + (size_t)(16*w + l15)*CNUM;
    const unsigned short* ar1 = ct16 + (size_t)(16*(w+8) + l15)*CNUM;
    const char* br0 = (const char*)S + (size_t)l15*2048;
    const char* br1 = (const char*)S + (size_t)(16+l15)*2048;
    const int bswz = (l15&7)<<4;
    #pragma unroll 8
    for (int s=0;s<32;s++){
      bf16x8 b0 = *reinterpret_cast<const bf16x8*>(br0 + ((64*s + 16*g) ^ bswz));
      bf16x8 b1 = *reinterpret_cast<const bf16x8*>(br1 + ((64*s + 16*g) ^ bswz));
      bf16x8 a0 = *reinterpret_cast<const bf16x8*>(ar0 + 32*s + 8*g);
      bf16x8 a1 = *reinterpret_cast<const bf16x8*>(ar1 + 32*s + 8*g);
      z00 = __builtin_amdgcn_mfma_f32_16x16x32_bf16(a0, b0, z00, 0,0,0);
      z01 = __builtin_amdgcn_mfma_f32_16x16x32_bf16(a0, b1, z01, 0,0,0);
      z10 = __builtin_amdgcn_mfma_f32_16x16x32_bf16(a1, b0, z10, 0,0,0);
      z11 = __builtin_amdgcn_mfma_f32_16x16x32_bf16(a1, b1, z11, 0,0,0);
    }
    #pragma unroll
    for (int mi=0;mi<2;mi++){
      #pragma unroll
      for (int nt=0;nt<2;nt++){
        f32x4 ac = (mi==0) ? (nt==0 ? z00 : z01) : (nt==0 ? z10 : z11);
        int mt = w + 8*mi;
        int t  = nt*16 + l15;
        int d0 = 16*mt + 4*g;
        unsigned w0 = (unsigned)f2bf(clamp11(ac[0])) | ((unsigned)f2bf(clamp11(ac[1]))<<16);
        unsigned w1 = (unsigned)f2bf(clamp11(ac[2])) | ((unsigned)f2bf(clamp11(ac[3]))<<16);
        *reinterpret_cast<uint2*>((char*)H + t*512 + ((2*d0) ^ ((t&7)<<4))) = make_uint2(w0,w1);
      }
    }
  }
  __syncthreads();

  // ---- P4: zsoft stores ----
  #pragma unroll
  for (int it=0; it<4; ++it){
    int e = tid + 512*it;
    int d = e>>3, q = e&7;
    float vv[4];
    #pragma unroll
    for (int u=0;u<4;u++){
      int t = 4*q + u;
      vv[u] = bf2f(*(const unsigned short*)((const char*)H + t*512 + ((2*d) ^ ((t&7)<<4))));
    }
    nt_store4(out + OFF_ZSOFT + (size_t)bb*262144 + (size_t)d*1024 + hw0 + 4*q,
              vv[0], vv[1], vv[2], vv[3]);
  }
}

// ---------- K2 (fallback only, R19-verbatim minus FUSE branch) ----------
__global__ __launch_bounds__(512, 4) void k2_soft_fb(const float* __restrict__ data,
                                                     const float* __restrict__ centers,
                                                     const unsigned short* __restrict__ scr16,
                                                     float* __restrict__ out){
  __shared__ unsigned short S[32*1024];
  __shared__ unsigned short H[32*256];

  const int tid = threadIdx.x;
  const int lane = tid&63;
  const int sb = (blockIdx.x & 7)*256 + (blockIdx.x >> 3);
  const int tok0 = sb*32;
  const int bb = tok0>>10, hw0 = tok0&1023;
  const unsigned short* sqblk = scr16 + (size_t)sb*32768;

  #pragma unroll
  for (int it=0; it<8; it++){
    int e = tid + 512*it;
    int t = e>>7, c8 = e&127;
    uint4 v = *reinterpret_cast<const uint4*>(sqblk + t*1024 + 8*c8);
    *reinterpret_cast<uint4*>((char*)S + t*2048 + ((16*c8) ^ ((t&7)<<4))) = v;
  }
  __syncthreads();

  for (int p=0;p<2;p++){
    const int t = p*16 + (tid>>5);
    const int j = tid&31;
    const int hb = (lane>=32)?32:0;
    const int tswz = (t&7)<<4;
    char* srow = (char*)S + t*2048;

    float a[32];
    float mns = 3.4e38f;
    #pragma unroll
    for (int i=0;i<32;i++){
      float sp = bf2f(*(const unsigned short*)(srow + ((2*(j+32*i)) ^ tswz)));
      a[i] = sp;
      mns = fminf(mns, sp);
    }
    #pragma unroll
    for (int m=16;m>=1;m>>=1) mns = fminf(mns, __shfl_xor(mns, m));
    float thr = mns + EPS_CAND;
    unsigned cm = 0;
    #pragma unroll
    for (int i=0;i<32;i++) if (a[i] < thr) cm |= (1u<<i);

    double bestd = 1.0e300; int bestk = CNUM;
    const float* xp = data + (size_t)bb*262144 + hw0 + t;
    for(;;){
      unsigned long long bal = __ballot(cm != 0);
      unsigned half = (lane<32)? (unsigned)(bal & 0xffffffffULL) : (unsigned)(bal>>32);
      if (!half) break;
      int src = __ffs(half)-1;
      unsigned cmsrc = (unsigned)__shfl((int)cm, hb + src);
      int ii = __ffs(cmsrc)-1;
      int k = src + 32*ii;
      if (j==src) cm &= ~(1u<<ii);
      double acc = 0.0;
      const float* crow = centers + (size_t)k*CDIM;
      #pragma unroll
      for (int q2=0;q2<8;q2++){
        double xv = (double)xp[(size_t)(j+32*q2)*1024];
        double ev = (double)crow[j+32*q2];
        double df = xv-ev; acc = fma(df,df,acc);
      }
      #pragma unroll
      for (int m=16;m>=1;m>>=1) acc += __shfl_xor(acc, m);
      if (acc < bestd || (acc==bestd && k<bestk)){ bestd=acc; bestk=k; }
    }
    if (j==0) out[OFF_SYM + tok0 + t] = (float)bestk;

    float dmn = sqrtf(fmaxf(mns, 0.f));
    float sum = 0.f;
    #pragma unroll
    for (int i=0;i<32;i++){
      float d = sqrtf(fmaxf(a[i], 0.f));
      a[i] = __expf(dmn - d);
      sum += a[i];
    }
    #pragma unroll
    for (int m=16;m>=1;m>>=1) sum += __shfl_xor(sum, m);
    float rs = 1.f/sum;
    #pragma unroll
    for (int i=0;i<32;i++){
      *(unsigned short*)(srow + ((2*(j+32*i)) ^ tswz)) = f2bf(clamp01(a[i]*rs));
    }
    const float* hrow = centers + (size_t)bestk*CDIM;
    #pragma unroll
    for (int q2=0;q2<8;q2++){
      int c = j + 32*q2;
      *(unsigned short*)((char*)H + t*512 + ((2*c) ^ tswz)) = f2bf(hrow[c]);
    }
  }
  __syncthreads();

  #pragma unroll
  for (int it=0; it<16; ++it){
    int e = tid + 512*it;
    int c = e>>3, q = e&7;
    float vv[4];
    #pragma unroll
    for (int u=0;u<4;u++){
      int t = 4*q + u;
      vv[u] = bf2f(*(const unsigned short*)((const char*)S + t*2048 + ((2*c) ^ ((t&7)<<4))));
    }
    nt_store4(out + OFF_PHI + (size_t)bb*1048576 + (size_t)c*1024 + hw0 + 4*q,
              vv[0], vv[1], vv[2], vv[3]);
  }
  #pragma unroll
  for (int it=0; it<4; ++it){
    int e = tid + 512*it;
    int d = e>>3, q = e&7;
    float vv[4];
    #pragma unroll
    for (int u=0;u<4;u++){
      int t = 4*q + u;
      vv[u] = bf2f(*(const unsigned short*)((const char*)H + t*512 + ((2*d) ^ ((t&7)<<4))));
    }
    nt_store4(out + OFF_ZBAR + (size_t)bb*262144 + (size_t)d*1024 + hw0 + 4*q,
              vv[0], vv[1], vv[2], vv[3]);
  }
}

// ---------- K3 (fallback only): GEMM2 from phi fp32 ----------
__global__ __launch_bounds__(512) void k3_gemm2(const float* __restrict__ phi,
                                                const unsigned short* __restrict__ ct16,
                                                float* __restrict__ zsoft){
  __shared__ unsigned short pls[64*64];
  const int tid = threadIdx.x;
  const int w = tid>>6, lane = tid&63;
  const int l15 = lane&15, g = lane>>4;
  const int b = blockIdx.x>>4, hw0 = (blockIdx.x&15)*64;

  f32x4 acc[2][4];
  #pragma unroll
  for (int h=0;h<2;h++)
    #pragma unroll
    for (int t2=0;t2<4;t2++) acc[h][t2] = (f32x4){0.f,0.f,0.f,0.f};

  for (int ks=0; ks<16; ks++){
    int k0s = ks*64;
    __syncthreads();
    #pragma unroll
    for (int it=0; it<4; it++){
      int e = tid + 512*it;
      int kp = e>>6, t = e&63;
      const float* pp = phi + (size_t)b*1048576 + (size_t)(k0s + 2*kp)*1024 + hw0 + t;
      float v0 = pp[0];
      float v1 = pp[1024];
      unsigned pk = (unsigned)f2bf(v0) | ((unsigned)f2bf(v1)<<16);
      int kk = 2*kp;
      int s = kk>>3;
      *reinterpret_cast<unsigned*>((char*)pls + t*128 + ((s ^ (t&7))<<4) + (kk&7)*2) = pk;
    }
    __syncthreads();
    #pragma unroll
    for (int ki=0; ki<2; ki++){
      int kk0 = k0s + 32*ki;
      bf16x8 a0 = *reinterpret_cast<const bf16x8*>(ct16 + (size_t)(32*w + l15)*CNUM + kk0 + 8*g);
      bf16x8 a1 = *reinterpret_cast<const bf16x8*>(ct16 + (size_t)(32*w + 16 + l15)*CNUM + kk0 + 8*g);
      #pragma unroll
      for (int t2=0;t2<4;t2++){
        int t = 16*t2 + l15;
        bf16x8 bf = *reinterpret_cast<const bf16x8*>((const char*)pls + t*128 + (((4*ki+g) ^ (t&7))<<4));
        acc[0][t2] = __builtin_amdgcn_mfma_f32_16x16x32_bf16(a0, bf, acc[0][t2], 0,0,0);
        acc[1][t2] = __builtin_amdgcn_mfma_f32_16x16x32_bf16(a1, bf, acc[1][t2], 0,0,0);
      }
    }
  }
  #pragma unroll
  for (int h=0;h<2;h++)
    #pragma unroll
    for (int t2=0;t2<4;t2++)
      #pragma unroll
      for (int r=0;r<4;r++){
        int d = 32*w + 16*h + 4*g + r;
        zsoft[(size_t)b*262144 + (size_t)d*1024 + hw0 + 16*t2 + l15] = clamp11(acc[h][t2][r]);
      }
}

extern "C" void kernel_launch(void* const* d_in, const int* in_sizes, int n_in,
                              void* d_out, int out_size, void* d_ws, size_t ws_size,
                              hipStream_t stream) {
  const float* data    = (const float*)d_in[0];
  const float* centers = (const float*)d_in[1];
  float* out           = (float*)d_out;

  const size_t SQ_BYTES = (size_t)1024*65536*2;   // 134,217,728
  const bool wsmode = (ws_size >= SQ_BYTES + 524288 + 524288 + 4096);

  unsigned short *scr16, *cb16, *ct16;
  float *e2;
  if (wsmode){
    scr16 = (unsigned short*)d_ws;
    cb16  = (unsigned short*)((char*)d_ws + SQ_BYTES);
    ct16  = (unsigned short*)((char*)d_ws + SQ_BYTES + 524288);
    e2    = (float*)((char*)d_ws + SQ_BYTES + 1048576);
  } else {
    scr16 = (unsigned short*)(out + OFF_ZSOFT);
    cb16  = (unsigned short*)d_ws;
    ct16  = (unsigned short*)((char*)d_ws + 524288);
    e2    = (float*)((char*)d_ws + 1048576);
  }

  prep_convert<<<dim3(256), dim3(256), 0, stream>>>(centers, cb16, ct16);
  prep_e2<<<dim3(4), dim3(256), 0, stream>>>(centers, e2);
  k1_gemm1<<<dim3(1024), dim3(512), 0, stream>>>(data, cb16, e2, scr16);
  if (wsmode){
    ka_soft<<<dim3(8192), dim3(256), 0, stream>>>(data, centers, scr16, out + OFF_SYM);
    kb_emit<<<dim3(2048), dim3(512), 0, stream>>>(centers, ct16, scr16, out);
  } else {
    k2_soft_fb<<<dim3(2048), dim3(512), 0, stream>>>(data, centers, scr16, out);
    hipMemcpyAsync(out + OFF_ZHARD, out + OFF_ZBAR, (size_t)16777216*4, hipMemcpyDeviceToDevice, stream);
    k3_gemm2<<<dim3(1024), dim3(512), 0, stream>>>(out + OFF_PHI, ct16, out + OFF_ZSOFT);
  }
}